// Round 9
// baseline (139.699 us; speedup 1.0000x reference)
//
#include <hip/hip_runtime.h>

// R9: R7 structure (s_load weights, no LDS, ROWS=2, packed fp32, exp2-domain,
// Montgomery-batched sigmoid rcps) with v_exp_f32 replaced by a bit-trick
// exp2 built from 6 full-rate VALU ops (12cy vs 16cy trans):
//   exponent field via float->u32 convert of (xp+127)*2^23, mantissa via
//   endpoint-exact correction 2^f = 1+f+(f^2-f)(a+bf), |rel err| <= 4.3e-4.
// Avoids R4's failure modes: no ldexpf (libcall), no v2f extract churn
// (scalar chain), clamp at -126 folded into one packed max per arg-pair.
// Per-wave demand: 20k -> 16.9k cy (-15.5%). rcp stays on the trans unit.

typedef float v2f __attribute__((ext_vector_type(2)));

#define LOG2E 1.44269504088896340736f
#define ROWS 2

__device__ __forceinline__ float rcpf(float a) { return __builtin_amdgcn_rcpf(a); }

#if __has_builtin(__builtin_amdgcn_fractf)
__device__ __forceinline__ float fract_fast(float a) { return __builtin_amdgcn_fractf(a); }
#else
__device__ __forceinline__ float fract_fast(float a) { return a - floorf(a); }
#endif

// 2^x for x in [-126, 127] (clamp upstream). 6 full-rate VALU insts.
// f = fract(x); mantissa = f + (f^2-f)*(a+b f)  (exact at f=0,1 -> continuous
// across integer boundaries); bits = (x + mant_corr + 127)*2^23 as u32.
__device__ __forceinline__ float exp2_bits(float x) {
    const float f  = fract_fast(x);
    const float u  = __builtin_fmaf(f, f, -f);               // f^2 - f in [-0.25,0]
    const float w  = __builtin_fmaf(0.079441542f, f, 0.305152655f);
    const float xp = __builtin_fmaf(u, w, x);                // x + (2^f - 1 - f)
    const float y  = __builtin_fmaf(xp, 8388608.f, 1065353216.f); // (xp+127)*2^23, > 0
    const unsigned i = (unsigned)y;                          // v_cvt_u32_f32
    return __builtin_bit_cast(float, i);
}

__device__ __forceinline__ v2f pexp2(v2f a) {               // a pre-clamped >= -126
    v2f e; e[0] = exp2_bits(a[0]); e[1] = exp2_bits(a[1]);
    return e;
}

__global__ __launch_bounds__(256, 4) void fused_attn_mlp(
    const float* __restrict__ x,
    const float* __restrict__ wq,
    const float* __restrict__ wk,
    const float* __restrict__ wv,
    const float* __restrict__ Wh,
    const float* __restrict__ bh,
    const float* __restrict__ Wo,
    const float* __restrict__ bo,
    float* __restrict__ out,
    int B)
{
    const int t = threadIdx.x;
    const int b0 = blockIdx.x * (256 * ROWS) + t;

    bool valid[ROWS];
    #pragma unroll
    for (int r = 0; r < ROWS; ++r) valid[r] = (b0 + r * 256) < B;

    // ---- issue x loads first ----
    float4 xraw[ROWS][4];
    #pragma unroll
    for (int r = 0; r < ROWS; ++r) {
        if (valid[r]) {
            const float4* xr = reinterpret_cast<const float4*>(x) + (size_t)(b0 + r * 256) * 4;
            xraw[r][0] = xr[0]; xraw[r][1] = xr[1]; xraw[r][2] = xr[2]; xraw[r][3] = xr[3];
        } else {
            xraw[r][0] = xraw[r][1] = xraw[r][2] = xraw[r][3] = float4{0.f,0.f,0.f,0.f};
        }
    }

    // ---- unpack x rows ----
    float xs[ROWS][16];
    v2f xv2[ROWS][8];
    #pragma unroll
    for (int r = 0; r < ROWS; ++r) {
        xs[r][0]=xraw[r][0].x; xs[r][1]=xraw[r][0].y; xs[r][2]=xraw[r][0].z; xs[r][3]=xraw[r][0].w;
        xs[r][4]=xraw[r][1].x; xs[r][5]=xraw[r][1].y; xs[r][6]=xraw[r][1].z; xs[r][7]=xraw[r][1].w;
        xs[r][8]=xraw[r][2].x; xs[r][9]=xraw[r][2].y; xs[r][10]=xraw[r][2].z; xs[r][11]=xraw[r][2].w;
        xs[r][12]=xraw[r][3].x; xs[r][13]=xraw[r][3].y; xs[r][14]=xraw[r][3].z; xs[r][15]=xraw[r][3].w;
        #pragma unroll
        for (int p = 0; p < 8; ++p) { v2f v; v[0]=xs[r][2*p]; v[1]=xs[r][2*p+1]; xv2[r][p]=v; }
    }

    const v2f nclamp = (v2f)(-126.f);

    // ---- attention block 1 (D=16), exp2 domain ----
    const float kq1 = wk[0] * wq[0] * LOG2E;
    const float v1  = wv[0];

    float xmx[ROWS], xmn[ROWS];
    #pragma unroll
    for (int r = 0; r < ROWS; ++r) {
        float mx = xs[r][0], mn = xs[r][0];
        #pragma unroll
        for (int i = 1; i < 16; ++i) { mx = fmaxf(mx, xs[r][i]); mn = fminf(mn, xs[r][i]); }
        xmx[r] = mx; xmn[r] = mn;
    }

    v2f o1v[ROWS][8];
    #pragma unroll
    for (int r = 0; r < ROWS; ++r)
        #pragma unroll
        for (int p = 0; p < 8; ++p) o1v[r][p] = (v2f)(0.f);

    #pragma unroll
    for (int i = 0; i < 16; ++i) {
        v2f e2[ROWS][8];
        float w[ROWS];
        #pragma unroll
        for (int r = 0; r < ROWS; ++r) {
            const float c = kq1 * xs[r][i];
            const float m = fmaxf(c * xmx[r], c * xmn[r]);   // exact attained max -> args <= 0
            v2f cc; cc[0]=c; cc[1]=c;
            v2f mm; mm[0]=m; mm[1]=m;
            #pragma unroll
            for (int p = 0; p < 8; ++p) {
                v2f a = cc * xv2[r][p] - mm;                 // v_pk_fma_f32
                a = __builtin_elementwise_max(a, nclamp);    // v_pk_max_f32
                e2[r][p] = pexp2(a);
            }
            v2f s01 = e2[r][0] + e2[r][1];
            v2f s23 = e2[r][2] + e2[r][3];
            v2f s45 = e2[r][4] + e2[r][5];
            v2f s67 = e2[r][6] + e2[r][7];
            v2f sv  = (s01 + s23) + (s45 + s67);
            w[r] = v1 * xs[r][i] * rcpf(sv[0] + sv[1]);
        }
        #pragma unroll
        for (int r = 0; r < ROWS; ++r) {
            v2f ww; ww[0]=w[r]; ww[1]=w[r];
            #pragma unroll
            for (int p = 0; p < 8; ++p) o1v[r][p] += ww * e2[r][p];
        }
    }

    // ---- fused MLP: 16 -> 64 sigmoid -> 8. Uniform-index weight reads ->
    //      s_load. Sigmoid rcps Montgomery-batched (groups of 4). ----
    v2f x2v[ROWS][4];
    #pragma unroll
    for (int r = 0; r < ROWS; ++r)
        #pragma unroll
        for (int p = 0; p < 4; ++p) { v2f v; v[0]=bo[2*p]; v[1]=bo[2*p+1]; x2v[r][p]=v; }

    const v2f* Wh2 = reinterpret_cast<const v2f*>(Wh);   // [64][8] pairs

    #pragma unroll 2
    for (int g = 0; g < 16; ++g) {
        float apre[ROWS][4];
        #pragma unroll
        for (int hh = 0; hh < 4; ++hh) {
            const int h = g * 4 + hh;
            v2f whr[8];
            #pragma unroll
            for (int p = 0; p < 8; ++p) whr[p] = Wh2[h * 8 + p];   // uniform -> s_load
            const float bhh = bh[h];
            #pragma unroll
            for (int r = 0; r < ROWS; ++r) {
                v2f acc = whr[0] * o1v[r][0];
                #pragma unroll
                for (int p = 1; p < 8; ++p) acc += whr[p] * o1v[r][p];
                apre[r][hh] = acc[0] + acc[1] + bhh;
            }
        }
        float sg[ROWS][4];
        #pragma unroll
        for (int r = 0; r < ROWS; ++r) {
            // clamp to [-126, 30]: upper bound keeps d <= 1+2^30 (prod4 <=
            // 2^121, no overflow); inert for any plausible activation.
            float d[4];
            #pragma unroll
            for (int hh = 0; hh < 4; ++hh) {
                const float la = fminf(fmaxf(-apre[r][hh] * LOG2E, -126.f), 30.f);
                d[hh] = 1.f + exp2_bits(la);
            }
            const float p01  = d[0] * d[1];
            const float p012 = p01 * d[2];
            const float rq   = rcpf(p012 * d[3]);
            const float i3 = rq * p012;
            const float tq = rq * d[3];      // 1/(d0 d1 d2)
            const float i2 = tq * p01;
            const float t2 = tq * d[2];      // 1/(d0 d1)
            sg[r][0] = t2 * d[1];
            sg[r][1] = t2 * d[0];
            sg[r][2] = i2;
            sg[r][3] = i3;
        }
        #pragma unroll
        for (int hh = 0; hh < 4; ++hh) {
            const int h = g * 4 + hh;
            #pragma unroll
            for (int p = 0; p < 4; ++p) {      // p = output pair (o = 2p, 2p+1)
                v2f wo2;
                wo2[0] = Wo[(2 * p) * 64 + h];       // uniform -> s_load
                wo2[1] = Wo[(2 * p + 1) * 64 + h];
                #pragma unroll
                for (int r = 0; r < ROWS; ++r) {
                    v2f sgv; sgv[0] = sg[r][hh]; sgv[1] = sg[r][hh];
                    x2v[r][p] += wo2 * sgv;
                }
            }
        }
    }

    // ---- attention block 2 (D=8), exp2 domain; LOG2E folded into o2 ----
    const float kq2 = wk[1] * wq[1] * LOG2E;
    const float v2s = wv[1] * LOG2E;

    float ys[ROWS][8];
    float ymx[ROWS], ymn[ROWS];
    #pragma unroll
    for (int r = 0; r < ROWS; ++r) {
        #pragma unroll
        for (int i = 0; i < 8; ++i) ys[r][i] = x2v[r][i >> 1][i & 1];
        float mx = ys[r][0], mn = ys[r][0];
        #pragma unroll
        for (int i = 1; i < 8; ++i) { mx = fmaxf(mx, ys[r][i]); mn = fminf(mn, ys[r][i]); }
        ymx[r] = mx; ymn[r] = mn;
    }

    v2f o2v[ROWS][4];
    #pragma unroll
    for (int r = 0; r < ROWS; ++r)
        #pragma unroll
        for (int p = 0; p < 4; ++p) o2v[r][p] = (v2f)(0.f);

    #pragma unroll
    for (int i = 0; i < 8; ++i) {
        v2f e2[ROWS][4];
        float w[ROWS];
        #pragma unroll
        for (int r = 0; r < ROWS; ++r) {
            const float c = kq2 * ys[r][i];
            const float m = fmaxf(c * ymx[r], c * ymn[r]);
            v2f cc; cc[0]=c; cc[1]=c;
            v2f mm; mm[0]=m; mm[1]=m;
            #pragma unroll
            for (int p = 0; p < 4; ++p) {
                v2f a = cc * x2v[r][p] - mm;
                a = __builtin_elementwise_max(a, nclamp);
                e2[r][p] = pexp2(a);
            }
            v2f sv = (e2[r][0] + e2[r][1]) + (e2[r][2] + e2[r][3]);
            w[r] = v2s * ys[r][i] * rcpf(sv[0] + sv[1]);
        }
        #pragma unroll
        for (int r = 0; r < ROWS; ++r) {
            v2f ww; ww[0]=w[r]; ww[1]=w[r];
            #pragma unroll
            for (int p = 0; p < 4; ++p) o2v[r][p] += ww * e2[r][p];
        }
    }

    // ---- final softmax (log2 domain) + dot with x[8:16] ----
    #pragma unroll
    for (int r = 0; r < ROWS; ++r) {
        float o2s[8];
        #pragma unroll
        for (int i = 0; i < 8; ++i) o2s[i] = o2v[r][i >> 1][i & 1];
        float m2 = o2s[0];
        #pragma unroll
        for (int i = 1; i < 8; ++i) m2 = fmaxf(m2, o2s[i]);
        v2f mm2; mm2[0]=m2; mm2[1]=m2;
        v2f se = (v2f)(0.f), de = (v2f)(0.f);
        #pragma unroll
        for (int p = 0; p < 4; ++p) {
            v2f a = o2v[r][p] - mm2;
            a = __builtin_elementwise_max(a, nclamp);
            v2f e = pexp2(a);
            se += e;
            v2f xp; xp[0]=xs[r][8+2*p]; xp[1]=xs[r][9+2*p];
            de += xp * e;
        }
        if (valid[r]) out[b0 + r * 256] = (de[0] + de[1]) * rcpf(se[0] + se[1]);
    }
}

extern "C" void kernel_launch(void* const* d_in, const int* in_sizes, int n_in,
                              void* d_out, int out_size, void* d_ws, size_t ws_size,
                              hipStream_t stream) {
    const float* x  = (const float*)d_in[0];
    const float* wq = (const float*)d_in[1];
    const float* wk = (const float*)d_in[2];
    const float* wv = (const float*)d_in[3];
    const float* Wh = (const float*)d_in[4];
    const float* bh = (const float*)d_in[5];
    const float* Wo = (const float*)d_in[6];
    const float* bo = (const float*)d_in[7];
    float* out = (float*)d_out;

    const int B = in_sizes[0] / 16;
    const int block = 256;
    const int rows_per_block = block * ROWS;
    const int grid = (B + rows_per_block - 1) / rows_per_block;
    fused_attn_mlp<<<grid, block, 0, stream>>>(x, wq, wk, wv, Wh, bh, Wo, bo, out, B);
}